// Round 12
// baseline (200.584 us; speedup 1.0000x reference)
//
#include <hip/hip_runtime.h>
#include <stdint.h>

// B=8, C=128, N=4096 (64x64), GROUPS=8 (16 ch/group)
// Split-KV flash attention, 32x32x16 MFMA quadrants, max-free base-2 softmax.
// R20: in-register P (cvt_pk + permlane32_swap, verified R2/R11) -> P_lds and
//      barrier B DELETED. Each wave: QK quadrant (32i x 32j) -> softmax in regs
//      -> PV over FULL C with acc[4] (64 regs) -> ONE barrier/iter (BAR_A,
//      vmcnt(0) only). Epilogue: jh-pair O reduce via K/V-buffer overlay
//      (wave-uniform branches, literal acc indices — R12-verified pattern).
//      LDS 80 -> 65 KiB; LDS reads 20 -> 16 b128/wave/iter.
//      (512,2) = 256-reg budget (R17 lesson); est need ~160-190. Spill
//      tripwire: WRITE_SIZE >> 35 MB => revert. gload_lds staging unchanged.

typedef __attribute__((ext_vector_type(8))) short short8;
typedef __attribute__((ext_vector_type(4))) float f32x4;
typedef __attribute__((ext_vector_type(16))) float f32x16;

#define MFMA_BF16(a, b, c) __builtin_amdgcn_mfma_f32_16x16x32_bf16((a), (b), (c), 0, 0, 0)
#define MFMA32(a, b, c) __builtin_amdgcn_mfma_f32_32x32x16_bf16((a), (b), (c), 0, 0, 0)
#define EXP2(x) __builtin_amdgcn_exp2f(x)

// (1/sqrt(128)) * log2(e) — folded into Q at k_qkv store time (softmax runs in base 2)
#define QSCALE 0.12751743f

__device__ __forceinline__ unsigned short f2bf(float f) {
    unsigned int u = __builtin_bit_cast(unsigned int, f);
    u += 0x7FFFu + ((u >> 16) & 1u);   // RNE (finite values only)
    return (unsigned short)(u >> 16);
}
__device__ __forceinline__ float bf2f(unsigned int lo16) {
    return __builtin_bit_cast(float, lo16 << 16);
}
__device__ __forceinline__ short8 ldg8(const unsigned short* p) {
    return __builtin_bit_cast(short8, *(const uint4*)p);
}
__device__ __forceinline__ unsigned int cvtpk(float lo, float hi) {
    unsigned int r;
    asm("v_cvt_pk_bf16_f32 %0, %1, %2" : "=v"(r) : "v"(lo), "v"(hi));
    return r;
}
__device__ __forceinline__ void gload16(const void* g, void* l) {
    __builtin_amdgcn_global_load_lds(
        (__attribute__((address_space(1))) void*)g,
        (__attribute__((address_space(3))) void*)l, 16, 0, 0);
}

// ---------------- Kernel 1: GroupNorm partial sums (atomic) + weight bf16 conv ------
__global__ __launch_bounds__(256) void k_pre(const float* __restrict__ x,
                                             float* __restrict__ sums,
                                             const float* __restrict__ qkv_w,
                                             const float* __restrict__ proj_w,
                                             unsigned short* __restrict__ wq,
                                             unsigned short* __restrict__ wp) {
    if (blockIdx.x >= 1024) {            // weight conversion: 64 blocks x 1024 elems
        int i = ((blockIdx.x - 1024) * 256 + threadIdx.x) * 4;
        const float* src; unsigned short* dst; int off;
        if (i < 49152) { src = qkv_w; dst = wq; off = i; }
        else           { src = proj_w; dst = wp; off = i - 49152; }
        float4 v = *(const float4*)(src + off);
        uint2 pk;
        pk.x = (unsigned int)f2bf(v.x) | ((unsigned int)f2bf(v.y) << 16);
        pk.y = (unsigned int)f2bf(v.z) | ((unsigned int)f2bf(v.w) << 16);
        *(uint2*)(dst + off) = pk;
        return;
    }
    int g     = blockIdx.x >> 4;         // 0..63 (b*8+gr); group slab contiguous
    int slice = blockIdx.x & 15;
    const float* p = x + (size_t)g * 65536 + slice * 4096;
    float s = 0.f, sq = 0.f;
#pragma unroll
    for (int i = 0; i < 4; ++i) {
        float4 v = *(const float4*)(p + threadIdx.x * 4 + i * 1024);
        s  += v.x + v.y + v.z + v.w;
        sq += v.x*v.x + v.y*v.y + v.z*v.z + v.w*v.w;
    }
#pragma unroll
    for (int m = 1; m < 64; m <<= 1) { s += __shfl_xor(s, m, 64); sq += __shfl_xor(sq, m, 64); }
    __shared__ float ss[4], ssq[4];
    int w = threadIdx.x >> 6;
    if ((threadIdx.x & 63) == 0) { ss[w] = s; ssq[w] = sq; }
    __syncthreads();
    if (threadIdx.x == 0) {
        atomicAdd(&sums[g * 2],     ss[0] + ss[1] + ss[2] + ss[3]);
        atomicAdd(&sums[g * 2 + 1], ssq[0] + ssq[1] + ssq[2] + ssq[3]);
    }
}

// ---------------- Kernel 2: fused GroupNorm-apply + QKV GEMM ----------------
// Q (pre-scaled by QSCALE), K as bf16 [b][n][c]; V as bf16 [b][c][n].
// V tiles computed transposed (MFMA(bfrag, af) -> D[n][c]) -> packed 8B global stores.
__global__ __launch_bounds__(256) void k_qkv(const float* __restrict__ x,
                                             const float* __restrict__ sums,
                                             const float* __restrict__ gn_w,
                                             const float* __restrict__ gn_b,
                                             const unsigned short* __restrict__ wq,
                                             const float* __restrict__ qkv_b,
                                             unsigned short* __restrict__ q_ws,
                                             unsigned short* __restrict__ k_ws,
                                             unsigned short* __restrict__ v_ws) {
    __shared__ unsigned short h_lds[64][136];   // [n][c], +8 pad
    const int tid  = threadIdx.x;
    const int b    = blockIdx.x >> 6;
    const int n0   = (blockIdx.x & 63) << 6;
    const int lane = tid & 63, wave = tid >> 6;
    const int l15  = lane & 15, q4 = lane >> 4;

    // normalize x tile -> bf16 -> h_lds[n][c]
    {
        int cb = tid >> 4;            // 0..15
        int nn = (tid & 15) << 2;     // 0..60
#pragma unroll
        for (int k = 0; k < 8; ++k) {
            int c = cb + (k << 4);
            float4 v = *(const float4*)(x + ((size_t)(b * 128 + c) << 12) + n0 + nn);
            int g = c >> 4;
            float ts = sums[(b * 8 + g) * 2];
            float tq = sums[(b * 8 + g) * 2 + 1];
            float mean = ts * (1.f / 65536.f);
            float var  = tq * (1.f / 65536.f) - mean * mean;
            float rstd = rsqrtf(var + 1e-5f);
            float ga = gn_w[c] * rstd;
            float be = gn_b[c] - mean * ga;
            h_lds[nn + 0][c] = f2bf(v.x * ga + be);
            h_lds[nn + 1][c] = f2bf(v.y * ga + be);
            h_lds[nn + 2][c] = f2bf(v.z * ga + be);
            h_lds[nn + 3][c] = f2bf(v.w * ga + be);
        }
    }
    __syncthreads();

    short8 bfrag[4][4];               // h[n][c]: as B (k=c, n=l15) or as A (m=n, k=c)
#pragma unroll
    for (int nt = 0; nt < 4; ++nt)
#pragma unroll
        for (int ks = 0; ks < 4; ++ks)
            bfrag[nt][ks] = *(const short8*)&h_lds[nt * 16 + l15][ks * 32 + q4 * 8];

#pragma unroll
    for (int ot = 0; ot < 6; ++ot) {
        int o0 = wave * 96 + ot * 16;                 // 16-row tile is purely Q, K, or V
        short8 af[4];                                 // w[o][c]: as A (m=o) or as B (n=o)
#pragma unroll
        for (int ks = 0; ks < 4; ++ks)
            af[ks] = ldg8(wq + (size_t)(o0 + l15) * 128 + ks * 32 + q4 * 8);

        if (o0 < 256) {               // Q or K: D[row=o(reg)][col=n=l15] -> [n][c] layout
            float bias[4];
#pragma unroll
            for (int r = 0; r < 4; ++r) bias[r] = qkv_b[o0 + q4 * 4 + r];
            float qs = (o0 < 128) ? QSCALE : 1.0f;
#pragma unroll
            for (int nt = 0; nt < 4; ++nt) {
                f32x4 acc = {0.f, 0.f, 0.f, 0.f};
#pragma unroll
                for (int ks = 0; ks < 4; ++ks)
                    acc = MFMA_BF16(af[ks], bfrag[nt][ks], acc);
                int n = n0 + nt * 16 + l15;
                unsigned short* dst = (o0 < 128) ? q_ws : k_ws;
                int oo = (o0 < 128) ? o0 : (o0 - 128);
                unsigned int lo = (unsigned int)f2bf((acc[0] + bias[0]) * qs) |
                                  ((unsigned int)f2bf((acc[1] + bias[1]) * qs) << 16);
                unsigned int hi = (unsigned int)f2bf((acc[2] + bias[2]) * qs) |
                                  ((unsigned int)f2bf((acc[3] + bias[3]) * qs) << 16);
                uint2 pk; pk.x = lo; pk.y = hi;
                *(uint2*)&dst[((size_t)(b * 4096 + n) << 7) + oo + q4 * 4] = pk;
            }
        } else {                      // V transposed: D[row=n(reg)][col=c=l15] -> [c][n]
            int c = o0 - 256 + l15;
            float vb = qkv_b[o0 + l15];
            unsigned short* vrow = v_ws + ((size_t)(b * 128 + c) << 12) + n0;
#pragma unroll
            for (int nt = 0; nt < 4; ++nt) {
                f32x4 acc = {0.f, 0.f, 0.f, 0.f};
#pragma unroll
                for (int ks = 0; ks < 4; ++ks)
                    acc = MFMA_BF16(bfrag[nt][ks], af[ks], acc);
                // n = nt*16 + q4*4 + r (4 consecutive) at fixed c -> packed 8B store
                unsigned int lo = (unsigned int)f2bf(acc[0] + vb) |
                                  ((unsigned int)f2bf(acc[1] + vb) << 16);
                unsigned int hi = (unsigned int)f2bf(acc[2] + vb) |
                                  ((unsigned int)f2bf(acc[3] + vb) << 16);
                uint2 pk; pk.x = lo; pk.y = hi;
                *(uint2*)&vrow[nt * 16 + q4 * 4] = pk;
            }
        }
    }
}

// ---------------- Kernel 3: flash attention partial (split-KV, 8 waves, i=128) ----
// block = 512 threads / 8 waves = (b, i-tile(128), chunk); chunk covers 1024 j.
// wave (ih 0..3, jh 0..1): QK quadrant S^T (32j regs x 32i lanes) -> in-register
// softmax -> cvt_pk+permlane32_swap builds the PV A-fragment -> PV over FULL C
// (acc[4]) from swizzled V_lds. NO P_lds, NO barrier B. One BAR_A per iter.
// Epilogue: jh-pair reduce via overlay (low-c in K0/K1, high-c in V0/V1).
// Swizzles: K key = r&15; V key = (c^(c>>3))&7 = vk ^ ((ct&1)<<2).
__global__ __launch_bounds__(512, 2) void k_attn_part(const unsigned short* __restrict__ q_ws,
                                                      const unsigned short* __restrict__ k_ws,
                                                      const unsigned short* __restrict__ v_ws,
                                                      unsigned short* __restrict__ o_part,
                                                      float* __restrict__ ml) {
    __shared__ unsigned short K0[64][128];      // 16 KB
    __shared__ unsigned short K1[64][128];      // 16 KB
    __shared__ unsigned short V0[128][64];      // 16 KB
    __shared__ unsigned short V1[128][64];      // 16 KB
    __shared__ float Lp[256];                   // 1 KB row-sum exchange -> 65 KiB

    const int tid   = threadIdx.x;              // 0..511
    const int chunk = blockIdx.x & 3;
    const int tile  = (blockIdx.x >> 2) & 31;
    const int b     = blockIdx.x >> 7;
    const int i0    = tile << 7;                // 128-row i-tile
    const int lane  = tid & 63, wave = tid >> 6;
    const int ih    = wave >> 1, jh = wave & 1;
    const int l31   = lane & 31, h = lane >> 5;

    // Q frags (pre-scaled by QSCALE): lane holds i = ih*32+l31, k=c=ks*16+h*8+e
    short8 qf[8];
    {
        const unsigned short* qp =
            q_ws + ((size_t)(b * 4096 + i0 + ih * 32 + l31) << 7) + h * 8;
#pragma unroll
        for (int ks = 0; ks < 8; ++ks) qf[ks] = ldg8(qp + ks * 16);
    }

    f32x16 acc[4];                           // O[i(reg)][c = ct*32 + l31], FULL C
#pragma unroll
    for (int ct = 0; ct < 4; ++ct)
#pragma unroll
        for (int e = 0; e < 16; ++e) acc[ct][e] = 0.f;
    float l_run = 0.f;

    // K staging: chunk c = q*512 + tid; dest linear; src slot = (c&15)^(row&15)
    const unsigned short* kbase = k_ws + ((size_t)b << 19) + ((size_t)chunk << 17);
    int ksrc[2];
#pragma unroll
    for (int q = 0; q < 2; ++q) {
        int c   = q * 512 + tid;
        int row = c >> 4;
        ksrc[q] = row * 16 + ((c & 15) ^ (row & 15));
    }
    // V staging: chunk c = q*512 + tid; row = c>>3 = q*64 + (tid>>3);
    // src s8 = (c&7) ^ key(row), key(row) = (row ^ (row>>3)) & 7 = ((tid>>3)&7) ^ wave
    const unsigned short* vlane = v_ws + ((size_t)b << 19) +
        ((size_t)(tid >> 3) << 12) + (chunk << 10) +
        ((((tid & 7) ^ ((tid >> 3) & 7) ^ wave)) << 3);

#define STAGE(T, KD, VD)                                                              \
  do {                                                                                \
    _Pragma("unroll")                                                                 \
    for (int q = 0; q < 2; ++q)                                                       \
      gload16(kbase + (size_t)(T) * 8192 + ksrc[q] * 8,                               \
              (char*)(&KD[0][0]) + q * 8192 + wave * 1024);                           \
    _Pragma("unroll")                                                                 \
    for (int q = 0; q < 2; ++q)                                                       \
      gload16(vlane + (size_t)q * 262144 + (T) * 64,                                  \
              (char*)(&VD[0][0]) + q * 8192 + wave * 1024);                           \
  } while (0)

// BAR_A: buf(t) DMA (issued 1 iter ago) visible -> vmcnt(0) only; all prior
// LDS reads were consumed by MFMAs pre-barrier (WAR safe). sched_barrier
// stops LDS reads from hoisting above the barrier (rule #18).
#define BAR_A()                                                                       \
  do {                                                                                \
    asm volatile("s_waitcnt vmcnt(0)" ::: "memory");                                  \
    __builtin_amdgcn_s_barrier();                                                     \
    __builtin_amdgcn_sched_barrier(0);                                                \
  } while (0)

    const int krow = jh * 32 + l31;
    const int ksw  = l31 & 15;                    // krow & 15
    const int vk   = (l31 & 7) ^ (l31 >> 3);      // V key base (^ ((ct&1)<<2) per ct)
    const int irow = ih * 32 + l31;

    // prologue: prefetch tile 0 -> buf0 (drained at first BAR_A)
    STAGE(0, K0, V0);

#define ATTN_ITER(IT, KR, VR, KP, VP)                                                 \
  do {                                                                                \
    BAR_A(); /* buf(IT) visible; all waves' LDS reads consumed */                     \
    if ((IT) < 15) STAGE((IT) + 1, KP, VP);   /* in flight until next BAR_A */        \
    f32x16 s; /* S^T quadrant: row j=(r&3)+8(r>>2)+4h (+jh*32), col i (lane) */       \
    _Pragma("unroll")                                                                 \
    for (int e = 0; e < 16; ++e) s[e] = 0.f;                                          \
    _Pragma("unroll")                                                                 \
    for (int ks = 0; ks < 8; ++ks) {                                                  \
      short8 kf = *(const short8*)&KR[krow][((ks * 2 + h) ^ ksw) << 3];               \
      s = MFMA32(kf, qf[ks], s);                                                      \
    }                                                                                 \
    float pvv[16]; /* max-free base-2 softmax, in registers */                        \
    _Pragma("unroll")                                                                 \
    for (int e = 0; e < 16; ++e) pvv[e] = EXP2(fminf(s[e], 30.f));                    \
    l_run += (((pvv[0] + pvv[1]) + (pvv[2] + pvv[3])) +                               \
              ((pvv[4] + pvv[5]) + (pvv[6] + pvv[7]))) +                              \
             (((pvv[8] + pvv[9]) + (pvv[10] + pvv[11])) +                             \
              ((pvv[12] + pvv[13]) + (pvv[14] + pvv[15])));                           \
    short8 paf[2]; /* PV A-frag: lane m=i, k = j(in-quadrant) = ks*16 + h*8 + e */    \
    _Pragma("unroll")                                                                 \
    for (int ks = 0; ks < 2; ++ks) {                                                  \
      const float* pp = pvv + ks * 8;                                                 \
      unsigned int Wa = cvtpk(pp[0], pp[1]);  /* h0: j01    h1: j45    (+16*ks) */    \
      unsigned int Wc = cvtpk(pp[2], pp[3]);  /* h0: j23    h1: j67    */             \
      unsigned int Wb = cvtpk(pp[4], pp[5]);  /* h0: j89    h1: j12,13 */             \
      unsigned int Wd = cvtpk(pp[6], pp[7]);  /* h0: j10,11 h1: j14,15 */             \
      auto r1 = __builtin_amdgcn_permlane32_swap(Wa, Wb, false, false);               \
      auto r2 = __builtin_amdgcn_permlane32_swap(Wc, Wd, false, false);               \
      uint4 aw; aw.x = r1[0]; aw.y = r2[0]; aw.z = r1[1]; aw.w = r2[1];               \
      paf[ks] = __builtin_bit_cast(short8, aw);   /* verified R2/R11 */               \
    }                                                                                 \
    _Pragma("unroll")                                                                 \
    for (int ks = 0; ks < 2; ++ks)                                                    \
      _Pragma("unroll")                                                               \
      for (int ct = 0; ct < 4; ++ct) {                                                \
        short8 vf = *(const short8*)&VR[ct * 32 + l31]                                \
            [((jh * 4 + ks * 2 + h) ^ vk ^ ((ct & 1) << 2)) << 3];                    \
        acc[ct] = MFMA32(paf[ks], vf, acc[ct]);                                       \
      }                                                                               \
  } while (0)

    for (int ib = 0; ib < 8; ++ib) {
        ATTN_ITER(ib * 2,     K0, V0, K1, V1);
        ATTN_ITER(ib * 2 + 1, K1, V1, K0, V0);
    }
#undef ATTN_ITER
#undef STAGE
#undef BAR_A

    // ---- epilogue: jh-pair reduce. Overlays: low-c in K0/K1, high-c in V0/V1.
    // Virtual row v = ih*32 + il (0..127): v<64 -> first array, else second.
    __syncthreads();                                 // full drain before overlay
    float l2 = l_run + __shfl_xor(l_run, 32);        // h-halves: disjoint j, same i
    if (h == 0) Lp[jh * 128 + irow] = l2;
    float* ObLow  = (ih < 2) ? (float*)&K0[0][0] : (float*)&K1[0][0];
    float* ObHigh = (ih < 2) ? (float*)&V0[0][0] : (float*)&V1[0][0];
    const int vbase = (ih & 1) * 32;                 // row offset within half-array
    if (jh) {                                        // deposit LOW c (acc[0,1])
#pragma unroll
        for (int cc = 0; cc < 2; ++cc)
#pragma unroll
            for (int r = 0; r < 16; ++r) {
                int il = (r & 3) + ((r >> 2) << 3) + (h << 2);
                ObLow[(vbase + il) * 64 + cc * 32 + l31] = (cc == 0) ? acc[0][r] : acc[1][r];
            }
    } else {                                         // deposit HIGH c (acc[2,3])
#pragma unroll
        for (int cc = 0; cc < 2; ++cc)
#pragma unroll
            for (int r = 0; r < 16; ++r) {
                int il = (r & 3) + ((r >> 2) << 3) + (h << 2);
                ObHigh[(vbase + il) * 64 + cc * 32 + l31] = (cc == 0) ? acc[2][r] : acc[3][r];
            }
    }
    __syncthreads();
    {
        float rl[16];
#pragma unroll
        for (int r = 0; r < 16; ++r) {
            int il = (r & 3) + ((r >> 2) << 3) + (h << 2);
            rl[r] = 1.0f / (Lp[ih * 32 + il] + Lp[128 + ih * 32 + il]);
        }
        if (jh) {                                    // finalize HIGH c: own acc[2,3]+ObHigh
#pragma unroll
            for (int cc = 0; cc < 2; ++cc)
#pragma unroll
                for (int r = 0; r < 16; ++r) {
                    int il = (r & 3) + ((r >> 2) << 3) + (h << 2);
                    float own = (cc == 0) ? acc[2][r] : acc[3][r];
                    float v = own + ObHigh[(vbase + il) * 64 + cc * 32 + l31];
                    int row = ih * 32 + il;
                    o_part[(((size_t)(b * 4096 + i0 + row) * 4 + chunk) << 7) +
                           64 + cc * 32 + l31] = f2bf(v * rl[r]);
                }
        } else {                                     // finalize LOW c: own acc[0,1]+ObLow
#pragma unroll
            for (int cc = 0; cc < 2; ++cc)
#pragma unroll
                for (int r = 0; r < 16; ++r) {
                    int il = (r & 3) + ((r >> 2) << 3) + (h << 2);
                    float own = (cc == 0) ? acc[0][r] : acc[1][r];
                    float v = own + ObLow[(vbase + il) * 64 + cc * 32 + l31];
                    int row = ih * 32 + il;
                    o_part[(((size_t)(b * 4096 + i0 + row) * 4 + chunk) << 7) +
                           cc * 32 + l31] = f2bf(v * rl[r]);
                }
        }
    }
    if (tid < 128) {
        // ml layout: [b][i 4096][chunk 4]
        ml[(b * 4096 + i0 + tid) * 4 + chunk] = __log2f(Lp[tid] + Lp[128 + tid]);
    }
}

// ---------------- Kernel 4: merge partials + proj GEMM + bias + residual ----------
__global__ __launch_bounds__(256) void k_merge_proj(const unsigned short* __restrict__ o_part,
                                                    const float* __restrict__ ml,
                                                    const float* __restrict__ x,
                                                    const unsigned short* __restrict__ wp,
                                                    const float* __restrict__ proj_b,
                                                    float* __restrict__ out) {
    __shared__ unsigned short O_lds[64][136];
    __shared__ float wgt[64][4];
    const int tid  = threadIdx.x;
    const int b    = blockIdx.x >> 6;
    const int tile = blockIdx.x & 63;
    const int i0   = tile << 6;
    const int lane = tid & 63, wave = tid >> 6;
    const int l15  = lane & 15, q4 = lane >> 4;

    if (tid < 64) {
        size_t mb = (size_t)(b * 4096 + i0 + tid) * 4;
        float m0 = ml[mb + 0], m1 = ml[mb + 1], m2 = ml[mb + 2], m3 = ml[mb + 3];
        float M = fmaxf(fmaxf(m0, m1), fmaxf(m2, m3));
        float w0 = EXP2(m0 - M), w1 = EXP2(m1 - M), w2 = EXP2(m2 - M), w3 = EXP2(m3 - M);
        float rW = 1.0f / (w0 + w1 + w2 + w3);
        wgt[tid][0] = w0 * rW; wgt[tid][1] = w1 * rW;
        wgt[tid][2] = w2 * rW; wgt[tid][3] = w3 * rW;
    }
    __syncthreads();

    {   // weighted merge: thread t -> row n=t>>2, 32-c quarter q=t&3
        int n = tid >> 2, q = tid & 3;
        float w[4];
#pragma unroll
        for (int ch = 0; ch < 4; ++ch) w[ch] = wgt[n][ch];
        size_t rbase = ((size_t)(b * 4096 + i0 + n) * 4) << 7;   // row's 4 partials
#pragma unroll
        for (int g = 0; g < 4; ++g) {             // 8 c per group
            float acc[8];
#pragma unroll
            for (int e = 0; e < 8; ++e) acc[e] = 0.f;
#pragma unroll
            for (int ch = 0; ch < 4; ++ch) {
                const unsigned short* p = o_part + rbase + (ch << 7) + q * 32 + g * 8;
                uint4 v = *(const uint4*)p;
                float wc = w[ch];
                acc[0] += wc * bf2f(v.x & 0xFFFF); acc[1] += wc * bf2f(v.x >> 16);
                acc[2] += wc * bf2f(v.y & 0xFFFF); acc[3] += wc * bf2f(v.y >> 16);
                acc[4] += wc * bf2f(v.z & 0xFFFF); acc[5] += wc * bf2f(v.z >> 16);
                acc[6] += wc * bf2f(v.w & 0xFFFF); acc[7] += wc * bf2f(v.w >> 16);
            }
            uint4 pk;
            pk.x = (unsigned int)f2bf(acc[0]) | ((unsigned int)f2bf(acc[1]) << 16);
            pk.y = (unsigned int)f2bf(acc[2]) | ((unsigned int)f2bf(acc[3]) << 16);
            pk.z = (unsigned int)f2bf(acc[4]) | ((unsigned int)f2bf(acc[5]) << 16);
            pk.w = (unsigned int)f2bf(acc[6]) | ((unsigned int)f2bf(acc[7]) << 16);
            *(uint4*)&O_lds[n][q * 32 + g * 8] = pk;
        }
    }
    __syncthreads();

    // proj GEMM: out[o][n] = sum_c proj_w[o][c] * O[n][c] + proj_b + x
    short8 bfrag[4][4];
#pragma unroll
    for (int nt = 0; nt < 4; ++nt)
#pragma unroll
        for (int ks = 0; ks < 4; ++ks)
            bfrag[nt][ks] = *(const short8*)&O_lds[nt * 16 + l15][ks * 32 + q4 * 8];

#pragma unroll
    for (int ot = 0; ot < 2; ++ot) {
        int o0 = wave * 32 + ot * 16;
        short8 af[4];
#pragma unroll
        for (int ks = 0; ks < 4; ++ks)
            af[ks] = ldg8(wp + (size_t)(o0 + l15) * 128 + ks * 32 + q4 * 8);
        float pb[4];
#pragma unroll
        for (int r = 0; r < 4; ++r) pb[r] = proj_b[o0 + q4 * 4 + r];

#pragma unroll
        for (int nt = 0; nt < 4; ++nt) {
            f32x4 acc = {0.f, 0.f, 0.f, 0.f};
#pragma unroll
            for (int ks = 0; ks < 4; ++ks)
                acc = MFMA_BF16(af[ks], bfrag[nt][ks], acc);
#pragma unroll
            for (int r = 0; r < 4; ++r) {
                size_t idx = ((size_t)(b * 128 + o0 + q4 * 4 + r) << 12) + i0 + nt * 16 + l15;
                out[idx] = x[idx] + acc[r] + pb[r];
            }
        }
    }
}

// ---------------- launch ----------------
extern "C" void kernel_launch(void* const* d_in, const int* in_sizes, int n_in,
                              void* d_out, int out_size, void* d_ws, size_t ws_size,
                              hipStream_t stream) {
    const float* x      = (const float*)d_in[0];
    const float* gn_w   = (const float*)d_in[1];
    const float* gn_b   = (const float*)d_in[2];
    const float* qkv_w  = (const float*)d_in[3];
    const float* qkv_b  = (const float*)d_in[4];
    const float* proj_w = (const float*)d_in[5];
    const float* proj_b = (const float*)d_in[6];
    float* out = (float*)d_out;

    char* ws = (char*)d_ws;
    float* sums           = (float*)ws;                              // 512 B (zeroed below)
    unsigned short* wq    = (unsigned short*)(ws + 4096);            // 96 KB
    unsigned short* wp    = (unsigned short*)(ws + 4096 + 98304);    // 32 KB
    unsigned short* q_ws  = (unsigned short*)(ws + ((size_t)1  << 20));  // 8 MB
    unsigned short* k_ws  = (unsigned short*)(ws + ((size_t)9  << 20));  // 8 MB
    unsigned short* v_ws  = (unsigned short*)(ws + ((size_t)17 << 20));  // 8 MB
    unsigned short* o_part= (unsigned short*)(ws + ((size_t)25 << 20));  // 32 MB
    float* ml             = (float*)(ws + ((size_t)57 << 20));           // 512 KB

    hipMemsetAsync(sums, 0, 512, stream);
    k_pre<<<1088, 256, 0, stream>>>(x, sums, qkv_w, proj_w, wq, wp);
    k_qkv<<<512, 256, 0, stream>>>(x, sums, gn_w, gn_b, wq, qkv_b, q_ws, k_ws, v_ws);
    k_attn_part<<<1024, 512, 0, stream>>>(q_ws, k_ws, v_ws, o_part, ml);
    k_merge_proj<<<512, 256, 0, stream>>>(o_part, ml, x, wp, proj_b, out);
}

// Round 15
// 179.747 us; speedup vs baseline: 1.1159x; 1.1159x over previous
//
#include <hip/hip_runtime.h>
#include <stdint.h>

// B=8, C=128, N=4096 (64x64), GROUPS=8 (16 ch/group)
// R21: chunk=1 flash attention + FUSED merge/proj epilogue.
//      Rationale: 1024-block split-KV ran 4 sequential rounds at 1 block/CU
//      anyway; chunk=1 (256 blocks = 1/CU) does the same j-work while
//      ELIMINATING o_part (32MB write + 32MB read), ml, and the entire
//      k_merge_proj kernel. Final O stays in acc; epilogue normalizes, puts
//      bf16 O in LDS, and runs proj GEMM + bias + residual (verbatim pattern
//      from the verified k_merge_proj, widened to 8 waves x 16 o-rows).
//      b = blockIdx&7 -> all 32 blocks of one batch (K/V = 2MB, fits 4MB L2)
//      land on one XCD.
//      Main loop = R20's verified body: in-register P (cvt_pk+permlane),
//      acc[4] full-C, ONE barrier/iter (vmcnt(0) only), gload_lds dbuf,
//      K key=r&15 / V key=(c^(c>>3))&7 swizzles, (512,2) bounds.
//      [Resubmit x2: rounds 13/14 were broker/container failures with empty
//       timing blocks — the kernel never compiled or ran.]

typedef __attribute__((ext_vector_type(8))) short short8;
typedef __attribute__((ext_vector_type(4))) float f32x4;
typedef __attribute__((ext_vector_type(16))) float f32x16;

#define MFMA_BF16(a, b, c) __builtin_amdgcn_mfma_f32_16x16x32_bf16((a), (b), (c), 0, 0, 0)
#define MFMA32(a, b, c) __builtin_amdgcn_mfma_f32_32x32x16_bf16((a), (b), (c), 0, 0, 0)
#define EXP2(x) __builtin_amdgcn_exp2f(x)

// (1/sqrt(128)) * log2(e) — folded into Q at k_qkv store time (softmax runs in base 2)
#define QSCALE 0.12751743f

__device__ __forceinline__ unsigned short f2bf(float f) {
    unsigned int u = __builtin_bit_cast(unsigned int, f);
    u += 0x7FFFu + ((u >> 16) & 1u);   // RNE (finite values only)
    return (unsigned short)(u >> 16);
}
__device__ __forceinline__ float bf2f(unsigned int lo16) {
    return __builtin_bit_cast(float, lo16 << 16);
}
__device__ __forceinline__ short8 ldg8(const unsigned short* p) {
    return __builtin_bit_cast(short8, *(const uint4*)p);
}
__device__ __forceinline__ unsigned int cvtpk(float lo, float hi) {
    unsigned int r;
    asm("v_cvt_pk_bf16_f32 %0, %1, %2" : "=v"(r) : "v"(lo), "v"(hi));
    return r;
}
__device__ __forceinline__ void gload16(const void* g, void* l) {
    __builtin_amdgcn_global_load_lds(
        (__attribute__((address_space(1))) void*)g,
        (__attribute__((address_space(3))) void*)l, 16, 0, 0);
}

// ---------------- Kernel 1: GroupNorm partial sums (atomic) + weight bf16 conv ------
__global__ __launch_bounds__(256) void k_pre(const float* __restrict__ x,
                                             float* __restrict__ sums,
                                             const float* __restrict__ qkv_w,
                                             const float* __restrict__ proj_w,
                                             unsigned short* __restrict__ wq,
                                             unsigned short* __restrict__ wp) {
    if (blockIdx.x >= 1024) {            // weight conversion: 64 blocks x 1024 elems
        int i = ((blockIdx.x - 1024) * 256 + threadIdx.x) * 4;
        const float* src; unsigned short* dst; int off;
        if (i < 49152) { src = qkv_w; dst = wq; off = i; }
        else           { src = proj_w; dst = wp; off = i - 49152; }
        float4 v = *(const float4*)(src + off);
        uint2 pk;
        pk.x = (unsigned int)f2bf(v.x) | ((unsigned int)f2bf(v.y) << 16);
        pk.y = (unsigned int)f2bf(v.z) | ((unsigned int)f2bf(v.w) << 16);
        *(uint2*)(dst + off) = pk;
        return;
    }
    int g     = blockIdx.x >> 4;         // 0..63 (b*8+gr); group slab contiguous
    int slice = blockIdx.x & 15;
    const float* p = x + (size_t)g * 65536 + slice * 4096;
    float s = 0.f, sq = 0.f;
#pragma unroll
    for (int i = 0; i < 4; ++i) {
        float4 v = *(const float4*)(p + threadIdx.x * 4 + i * 1024);
        s  += v.x + v.y + v.z + v.w;
        sq += v.x*v.x + v.y*v.y + v.z*v.z + v.w*v.w;
    }
#pragma unroll
    for (int m = 1; m < 64; m <<= 1) { s += __shfl_xor(s, m, 64); sq += __shfl_xor(sq, m, 64); }
    __shared__ float ss[4], ssq[4];
    int w = threadIdx.x >> 6;
    if ((threadIdx.x & 63) == 0) { ss[w] = s; ssq[w] = sq; }
    __syncthreads();
    if (threadIdx.x == 0) {
        atomicAdd(&sums[g * 2],     ss[0] + ss[1] + ss[2] + ss[3]);
        atomicAdd(&sums[g * 2 + 1], ssq[0] + ssq[1] + ssq[2] + ssq[3]);
    }
}

// ---------------- Kernel 2: fused GroupNorm-apply + QKV GEMM ----------------
// Q (pre-scaled by QSCALE), K as bf16 [b][n][c]; V as bf16 [b][c][n].
// V tiles computed transposed (MFMA(bfrag, af) -> D[n][c]) -> packed 8B global stores.
__global__ __launch_bounds__(256) void k_qkv(const float* __restrict__ x,
                                             const float* __restrict__ sums,
                                             const float* __restrict__ gn_w,
                                             const float* __restrict__ gn_b,
                                             const unsigned short* __restrict__ wq,
                                             const float* __restrict__ qkv_b,
                                             unsigned short* __restrict__ q_ws,
                                             unsigned short* __restrict__ k_ws,
                                             unsigned short* __restrict__ v_ws) {
    __shared__ unsigned short h_lds[64][136];   // [n][c], +8 pad
    const int tid  = threadIdx.x;
    const int b    = blockIdx.x >> 6;
    const int n0   = (blockIdx.x & 63) << 6;
    const int lane = tid & 63, wave = tid >> 6;
    const int l15  = lane & 15, q4 = lane >> 4;

    // normalize x tile -> bf16 -> h_lds[n][c]
    {
        int cb = tid >> 4;            // 0..15
        int nn = (tid & 15) << 2;     // 0..60
#pragma unroll
        for (int k = 0; k < 8; ++k) {
            int c = cb + (k << 4);
            float4 v = *(const float4*)(x + ((size_t)(b * 128 + c) << 12) + n0 + nn);
            int g = c >> 4;
            float ts = sums[(b * 8 + g) * 2];
            float tq = sums[(b * 8 + g) * 2 + 1];
            float mean = ts * (1.f / 65536.f);
            float var  = tq * (1.f / 65536.f) - mean * mean;
            float rstd = rsqrtf(var + 1e-5f);
            float ga = gn_w[c] * rstd;
            float be = gn_b[c] - mean * ga;
            h_lds[nn + 0][c] = f2bf(v.x * ga + be);
            h_lds[nn + 1][c] = f2bf(v.y * ga + be);
            h_lds[nn + 2][c] = f2bf(v.z * ga + be);
            h_lds[nn + 3][c] = f2bf(v.w * ga + be);
        }
    }
    __syncthreads();

    short8 bfrag[4][4];               // h[n][c]: as B (k=c, n=l15) or as A (m=n, k=c)
#pragma unroll
    for (int nt = 0; nt < 4; ++nt)
#pragma unroll
        for (int ks = 0; ks < 4; ++ks)
            bfrag[nt][ks] = *(const short8*)&h_lds[nt * 16 + l15][ks * 32 + q4 * 8];

#pragma unroll
    for (int ot = 0; ot < 6; ++ot) {
        int o0 = wave * 96 + ot * 16;                 // 16-row tile is purely Q, K, or V
        short8 af[4];                                 // w[o][c]: as A (m=o) or as B (n=o)
#pragma unroll
        for (int ks = 0; ks < 4; ++ks)
            af[ks] = ldg8(wq + (size_t)(o0 + l15) * 128 + ks * 32 + q4 * 8);

        if (o0 < 256) {               // Q or K: D[row=o(reg)][col=n=l15] -> [n][c] layout
            float bias[4];
#pragma unroll
            for (int r = 0; r < 4; ++r) bias[r] = qkv_b[o0 + q4 * 4 + r];
            float qs = (o0 < 128) ? QSCALE : 1.0f;
#pragma unroll
            for (int nt = 0; nt < 4; ++nt) {
                f32x4 acc = {0.f, 0.f, 0.f, 0.f};
#pragma unroll
                for (int ks = 0; ks < 4; ++ks)
                    acc = MFMA_BF16(af[ks], bfrag[nt][ks], acc);
                int n = n0 + nt * 16 + l15;
                unsigned short* dst = (o0 < 128) ? q_ws : k_ws;
                int oo = (o0 < 128) ? o0 : (o0 - 128);
                unsigned int lo = (unsigned int)f2bf((acc[0] + bias[0]) * qs) |
                                  ((unsigned int)f2bf((acc[1] + bias[1]) * qs) << 16);
                unsigned int hi = (unsigned int)f2bf((acc[2] + bias[2]) * qs) |
                                  ((unsigned int)f2bf((acc[3] + bias[3]) * qs) << 16);
                uint2 pk; pk.x = lo; pk.y = hi;
                *(uint2*)&dst[((size_t)(b * 4096 + n) << 7) + oo + q4 * 4] = pk;
            }
        } else {                      // V transposed: D[row=n(reg)][col=c=l15] -> [c][n]
            int c = o0 - 256 + l15;
            float vb = qkv_b[o0 + l15];
            unsigned short* vrow = v_ws + ((size_t)(b * 128 + c) << 12) + n0;
#pragma unroll
            for (int nt = 0; nt < 4; ++nt) {
                f32x4 acc = {0.f, 0.f, 0.f, 0.f};
#pragma unroll
                for (int ks = 0; ks < 4; ++ks)
                    acc = MFMA_BF16(bfrag[nt][ks], af[ks], acc);
                // n = nt*16 + q4*4 + r (4 consecutive) at fixed c -> packed 8B store
                unsigned int lo = (unsigned int)f2bf(acc[0] + vb) |
                                  ((unsigned int)f2bf(acc[1] + vb) << 16);
                unsigned int hi = (unsigned int)f2bf(acc[2] + vb) |
                                  ((unsigned int)f2bf(acc[3] + vb) << 16);
                uint2 pk; pk.x = lo; pk.y = hi;
                *(uint2*)&vrow[nt * 16 + q4 * 4] = pk;
            }
        }
    }
}

// ---------------- Kernel 3: FUSED flash attention + proj + residual ----------------
// grid = 256 blocks (b = blockIdx&7 -> batch-per-XCD L2 locality), 512 threads.
// Each block: one 128-row i-tile, ALL 4096 j (64 iters, dbuf). Main loop = R20.
// Epilogue: jh-pair O reduce (overlay deposit) -> normalize -> O_lds bf16 ->
// proj GEMM + bias + residual -> out. No o_part, no ml, no merge kernel.
__global__ __launch_bounds__(512, 2) void k_attn(const unsigned short* __restrict__ q_ws,
                                                 const unsigned short* __restrict__ k_ws,
                                                 const unsigned short* __restrict__ v_ws,
                                                 const float* __restrict__ x,
                                                 const unsigned short* __restrict__ wp,
                                                 const float* __restrict__ proj_b,
                                                 float* __restrict__ out) {
    __shared__ unsigned short K0[64][128];      // 16 KB
    __shared__ unsigned short K1[64][128];      // 16 KB
    __shared__ unsigned short V0[128][64];      // 16 KB
    __shared__ unsigned short V1[128][64];      // 16 KB
    __shared__ unsigned short O_lds[128][136];  // 34 KB  (proj input, +8 pad)
    __shared__ float Lp[256];                   // 1 KB   -> ~99 KiB total

    const int tid   = threadIdx.x;              // 0..511
    const int b     = blockIdx.x & 7;           // batch -> same XCD for same b
    const int tile  = blockIdx.x >> 3;          // 0..31
    const int i0    = tile << 7;                // 128-row i-tile
    const int lane  = tid & 63, wave = tid >> 6;
    const int ih    = wave >> 1, jh = wave & 1;
    const int l31   = lane & 31, h = lane >> 5;

    // Q frags (pre-scaled by QSCALE): lane holds i = ih*32+l31, k=c=ks*16+h*8+e
    short8 qf[8];
    {
        const unsigned short* qp =
            q_ws + ((size_t)(b * 4096 + i0 + ih * 32 + l31) << 7) + h * 8;
#pragma unroll
        for (int ks = 0; ks < 8; ++ks) qf[ks] = ldg8(qp + ks * 16);
    }

    f32x16 acc[4];                           // O[i(reg)][c = ct*32 + l31], FULL C
#pragma unroll
    for (int ct = 0; ct < 4; ++ct)
#pragma unroll
        for (int e = 0; e < 16; ++e) acc[ct][e] = 0.f;
    float l_run = 0.f;

    // K staging: chunk c = q*512 + tid; dest linear; src slot = (c&15)^(row&15)
    const unsigned short* kbase = k_ws + ((size_t)b << 19);
    int ksrc[2];
#pragma unroll
    for (int q = 0; q < 2; ++q) {
        int c   = q * 512 + tid;
        int row = c >> 4;
        ksrc[q] = row * 16 + ((c & 15) ^ (row & 15));
    }
    // V staging: chunk c = q*512 + tid; row = c>>3 = q*64 + (tid>>3);
    // src s8 = (c&7) ^ key(row), key(row) = ((tid>>3)&7) ^ wave
    const unsigned short* vlane = v_ws + ((size_t)b << 19) +
        ((size_t)(tid >> 3) << 12) +
        ((((tid & 7) ^ ((tid >> 3) & 7) ^ wave)) << 3);

#define STAGE(T, KD, VD)                                                              \
  do {                                                                                \
    _Pragma("unroll")                                                                 \
    for (int q = 0; q < 2; ++q)                                                       \
      gload16(kbase + (size_t)(T) * 8192 + ksrc[q] * 8,                               \
              (char*)(&KD[0][0]) + q * 8192 + wave * 1024);                           \
    _Pragma("unroll")                                                                 \
    for (int q = 0; q < 2; ++q)                                                       \
      gload16(vlane + (size_t)q * 262144 + (T) * 64,                                  \
              (char*)(&VD[0][0]) + q * 8192 + wave * 1024);                           \
  } while (0)

// BAR_A: buf(t) DMA (issued 1 iter ago) visible -> vmcnt(0) only; prior LDS
// reads were consumed by MFMAs (WAR safe). sched_barrier: rule #18.
#define BAR_A()                                                                       \
  do {                                                                                \
    asm volatile("s_waitcnt vmcnt(0)" ::: "memory");                                  \
    __builtin_amdgcn_s_barrier();                                                     \
    __builtin_amdgcn_sched_barrier(0);                                                \
  } while (0)

    const int krow = jh * 32 + l31;
    const int ksw  = l31 & 15;                    // krow & 15
    const int vk   = (l31 & 7) ^ (l31 >> 3);      // V key base (^ ((ct&1)<<2) per ct)
    const int irow = ih * 32 + l31;

    // prologue: prefetch tile 0 -> buf0 (drained at first BAR_A)
    STAGE(0, K0, V0);

#define ATTN_ITER(IT, KR, VR, KP, VP)                                                 \
  do {                                                                                \
    BAR_A(); /* buf visible; all waves' LDS reads consumed */                         \
    if ((IT) < 63) STAGE((IT) + 1, KP, VP);   /* in flight until next BAR_A */        \
    f32x16 s; /* S^T quadrant: row j=(r&3)+8(r>>2)+4h (+jh*32), col i (lane) */       \
    _Pragma("unroll")                                                                 \
    for (int e = 0; e < 16; ++e) s[e] = 0.f;                                          \
    _Pragma("unroll")                                                                 \
    for (int ks = 0; ks < 8; ++ks) {                                                  \
      short8 kf = *(const short8*)&KR[krow][((ks * 2 + h) ^ ksw) << 3];               \
      s = MFMA32(kf, qf[ks], s);                                                      \
    }                                                                                 \
    float pvv[16]; /* max-free base-2 softmax, in registers */                        \
    _Pragma("unroll")                                                                 \
    for (int e = 0; e < 16; ++e) pvv[e] = EXP2(fminf(s[e], 30.f));                    \
    l_run += (((pvv[0] + pvv[1]) + (pvv[2] + pvv[3])) +                               \
              ((pvv[4] + pvv[5]) + (pvv[6] + pvv[7]))) +                              \
             (((pvv[8] + pvv[9]) + (pvv[10] + pvv[11])) +                             \
              ((pvv[12] + pvv[13]) + (pvv[14] + pvv[15])));                           \
    short8 paf[2]; /* PV A-frag: lane m=i, k = j(in-quadrant) = ks*16 + h*8 + e */    \
    _Pragma("unroll")                                                                 \
    for (int ks = 0; ks < 2; ++ks) {                                                  \
      const float* pp = pvv + ks * 8;                                                 \
      unsigned int Wa = cvtpk(pp[0], pp[1]);                                          \
      unsigned int Wc = cvtpk(pp[2], pp[3]);                                          \
      unsigned int Wb = cvtpk(pp[4], pp[5]);                                          \
      unsigned int Wd = cvtpk(pp[6], pp[7]);                                          \
      auto r1 = __builtin_amdgcn_permlane32_swap(Wa, Wb, false, false);               \
      auto r2 = __builtin_amdgcn_permlane32_swap(Wc, Wd, false, false);               \
      uint4 aw; aw.x = r1[0]; aw.y = r2[0]; aw.z = r1[1]; aw.w = r2[1];               \
      paf[ks] = __builtin_bit_cast(short8, aw);   /* verified R2/R11/R20 */           \
    }                                                                                 \
    _Pragma("unroll")                                                                 \
    for (int ks = 0; ks < 2; ++ks)                                                    \
      _Pragma("unroll")                                                               \
      for (int ct = 0; ct < 4; ++ct) {                                                \
        short8 vf = *(const short8*)&VR[ct * 32 + l31]                                \
            [((jh * 4 + ks * 2 + h) ^ vk ^ ((ct & 1) << 2)) << 3];                    \
        acc[ct] = MFMA32(paf[ks], vf, acc[ct]);                                       \
      }                                                                               \
  } while (0)

    for (int ib = 0; ib < 32; ++ib) {
        int it = ib * 2;
        ATTN_ITER(it,     K0, V0, K1, V1);
        ATTN_ITER(it + 1, K1, V1, K0, V0);
    }
#undef ATTN_ITER
#undef STAGE
#undef BAR_A

    // ---- epilogue 1: jh-pair O reduce (overlay deposit in K/V bufs, f32) ----
    __syncthreads();                                 // full drain before overlay
    float l2 = l_run + __shfl_xor(l_run, 32);        // h-halves: disjoint j, same i
    if (h == 0) Lp[jh * 128 + irow] = l2;
    float* ObLow  = (ih < 2) ? (float*)&K0[0][0] : (float*)&K1[0][0];
    float* ObHigh = (ih < 2) ? (float*)&V0[0][0] : (float*)&V1[0][0];
    const int vbase = (ih & 1) * 32;                 // row offset within half-array
    if (jh) {                                        // deposit LOW c (acc[0,1])
#pragma unroll
        for (int cc = 0; cc < 2; ++cc)
#pragma unroll
            for (int r = 0; r < 16; ++r) {
                int il = (r & 3) + ((r >> 2) << 3) + (h << 2);
                ObLow[(vbase + il) * 64 + cc * 32 + l31] = (cc == 0) ? acc[0][r] : acc[1][r];
            }
    } else {                                         // deposit HIGH c (acc[2,3])
#pragma unroll
        for (int cc = 0; cc < 2; ++cc)
#pragma unroll
            for (int r = 0; r < 16; ++r) {
                int il = (r & 3) + ((r >> 2) << 3) + (h << 2);
                ObHigh[(vbase + il) * 64 + cc * 32 + l31] = (cc == 0) ? acc[2][r] : acc[3][r];
            }
    }
    __syncthreads();
    // ---- epilogue 2: normalize + write bf16 O to O_lds ----
    {
        float rl[16];
#pragma unroll
        for (int r = 0; r < 16; ++r) {
            int il = (r & 3) + ((r >> 2) << 3) + (h << 2);
            rl[r] = 1.0f / (Lp[ih * 32 + il] + Lp[128 + ih * 32 + il]);
        }
        if (jh) {                                    // finalize HIGH c: own acc[2,3]+ObHigh
#pragma unroll
            for (int cc = 0; cc < 2; ++cc)
#pragma unroll
                for (int r = 0; r < 16; ++r) {
                    int il = (r & 3) + ((r >> 2) << 3) + (h << 2);
                    float own = (cc == 0) ? acc[2][r] : acc[3][r];
                    float v = own + ObHigh[(vbase + il) * 64 + cc * 32 + l31];
                    O_lds[ih * 32 + il][64 + cc * 32 + l31] = f2bf(v * rl[r]);
                }
        } else {                                     // finalize LOW c: own acc[0,1]+ObLow
#pragma unroll
            for (int cc = 0; cc < 2; ++cc)
#pragma unroll
                for (int r = 0; r < 16; ++r) {
                    int il = (r & 3) + ((r >> 2) << 3) + (h << 2);
                    float own = (cc == 0) ? acc[0][r] : acc[1][r];
                    float v = own + ObLow[(vbase + il) * 64 + cc * 32 + l31];
                    O_lds[ih * 32 + il][cc * 32 + l31] = f2bf(v * rl[r]);
                }
        }
    }
    __syncthreads();

    // ---- epilogue 3: proj GEMM + bias + residual (k_merge_proj pattern) ----
    // out[o][n] = sum_c proj_w[o][c] * O[n][c] + proj_b[o] + x[o][n]
    {
        const int l15 = lane & 15, q4 = lane >> 4;
        int o0 = wave * 16;                          // 8 waves x 16 o-rows = 128
        short8 af[4];
#pragma unroll
        for (int ks = 0; ks < 4; ++ks)
            af[ks] = ldg8(wp + (size_t)(o0 + l15) * 128 + ks * 32 + q4 * 8);
        float pb[4];
#pragma unroll
        for (int r = 0; r < 4; ++r) pb[r] = proj_b[o0 + q4 * 4 + r];

#pragma unroll
        for (int nt = 0; nt < 8; ++nt) {             // 8 x 16 = 128 n-rows
            f32x4 pacc = {0.f, 0.f, 0.f, 0.f};
#pragma unroll
            for (int ks = 0; ks < 4; ++ks) {
                short8 bf = *(const short8*)&O_lds[nt * 16 + l15][ks * 32 + q4 * 8];
                pacc = MFMA_BF16(af[ks], bf, pacc);
            }
#pragma unroll
            for (int r = 0; r < 4; ++r) {
                size_t idx = ((size_t)(b * 128 + o0 + q4 * 4 + r) << 12) +
                             i0 + nt * 16 + l15;
                out[idx] = x[idx] + pacc[r] + pb[r];
            }
        }
    }
}

// ---------------- launch ----------------
extern "C" void kernel_launch(void* const* d_in, const int* in_sizes, int n_in,
                              void* d_out, int out_size, void* d_ws, size_t ws_size,
                              hipStream_t stream) {
    const float* x      = (const float*)d_in[0];
    const float* gn_w   = (const float*)d_in[1];
    const float* gn_b   = (const float*)d_in[2];
    const float* qkv_w  = (const float*)d_in[3];
    const float* qkv_b  = (const float*)d_in[4];
    const float* proj_w = (const float*)d_in[5];
    const float* proj_b = (const float*)d_in[6];
    float* out = (float*)d_out;

    char* ws = (char*)d_ws;
    float* sums           = (float*)ws;                              // 512 B (zeroed below)
    unsigned short* wq    = (unsigned short*)(ws + 4096);            // 96 KB
    unsigned short* wp    = (unsigned short*)(ws + 4096 + 98304);    // 32 KB
    unsigned short* q_ws  = (unsigned short*)(ws + ((size_t)1  << 20));  // 8 MB
    unsigned short* k_ws  = (unsigned short*)(ws + ((size_t)9  << 20));  // 8 MB
    unsigned short* v_ws  = (unsigned short*)(ws + ((size_t)17 << 20));  // 8 MB

    hipMemsetAsync(sums, 0, 512, stream);
    k_pre<<<1088, 256, 0, stream>>>(x, sums, qkv_w, proj_w, wq, wp);
    k_qkv<<<512, 256, 0, stream>>>(x, sums, gn_w, gn_b, wq, qkv_b, q_ws, k_ws, v_ws);
    k_attn<<<256, 512, 0, stream>>>(q_ws, k_ws, v_ws, x, wp, proj_b, out);
}